// Round 11
// baseline (114.730 us; speedup 1.0000x reference)
//
#include <hip/hip_runtime.h>
#include <hip/hip_fp8.h>

#define NV 4
#define NB 2048
#define ND 512
#define NN 8192
// sim = cos/TEMP, TEMP=0.5 -> scale 2.0

typedef int int8v __attribute__((ext_vector_type(8)));
typedef int int4v __attribute__((ext_vector_type(4)));
typedef float floatx4 __attribute__((ext_vector_type(4)));
#define SCALE1 0x7F7F7F7Fu  // E8M0 bytes 127 -> 2^0 = 1.0

// ---------------- normalize: x[N,D] f32 -> xn[N,D] fp8 e4m3 (unit rows) ----
__global__ __launch_bounds__(256) void normalize_k(const float* __restrict__ x,
                                                   unsigned char* __restrict__ xn,
                                                   float* __restrict__ sumexp,
                                                   float* __restrict__ out) {
  if (threadIdx.x < 4) sumexp[blockIdx.x * 4 + threadIdx.x] = 0.0f;
  if (blockIdx.x == 0 && threadIdx.x == 0) out[0] = 0.0f;

  const int row = blockIdx.x * 4 + (threadIdx.x >> 6);  // one wave per row
  const int l = threadIdx.x & 63;
  const float4* xr = (const float4*)(x + (size_t)row * ND);
  float4 v0 = xr[l * 2 + 0];
  float4 v1 = xr[l * 2 + 1];
  float ss = v0.x * v0.x + v0.y * v0.y + v0.z * v0.z + v0.w * v0.w +
             v1.x * v1.x + v1.y * v1.y + v1.z * v1.z + v1.w * v1.w;
#pragma unroll
  for (int off = 32; off > 0; off >>= 1) ss += __shfl_xor(ss, off, 64);
  const float inv = 1.0f / fmaxf(sqrtf(ss), 1e-8f);
  union { unsigned char b[8]; uint2 u; } pk;
  pk.b[0] = __hip_fp8_e4m3(v0.x * inv).__x;
  pk.b[1] = __hip_fp8_e4m3(v0.y * inv).__x;
  pk.b[2] = __hip_fp8_e4m3(v0.z * inv).__x;
  pk.b[3] = __hip_fp8_e4m3(v0.w * inv).__x;
  pk.b[4] = __hip_fp8_e4m3(v1.x * inv).__x;
  pk.b[5] = __hip_fp8_e4m3(v1.y * inv).__x;
  pk.b[6] = __hip_fp8_e4m3(v1.z * inv).__x;
  pk.b[7] = __hip_fp8_e4m3(v1.w * inv).__x;
  *(uint2*)(xn + (size_t)row * ND + l * 8) = pk.u;
}

// ---------------- fused sim GEMM + exp/mask epilogue -------------------------
// R11: BARRIER-FREE. One wave (64-thread block) owns one 64x64 output tile;
// 8256 tiles over the 128-granular upper triangle. Each wave stages its OWN
// 16 KB LDS slab (A 8 KB + B 8 KB, XOR-swizzled: row r chunk c at
// r*128 + (c^(r&7))*16) and register-prefetches its next-kt globals. No
// inter-wave sharing -> zero s_barrier in the K-loop; only per-wave lgkmcnt
// waits, which the ~10 independently-phased waves/CU cover. Rationale: R8/R9/
// R10 all landed at ~49 us with pipes running sequentially (VALU 28% + LDS
// ~40% + MFMA 13% summing to the kernel) — barrier lockstep kept all waves in
// the same phase; this removes the lockstep at the cost of 2x staged writes.
// Diagonal tiles (rt==ct) reuse the A slab for B (skip B stage + loads).
__global__ __launch_bounds__(64, 2) void sim_k(const unsigned char* __restrict__ xn,
                                               float* __restrict__ sumexp,
                                               float* __restrict__ pos) {
  __shared__ unsigned char As[64 * 128];  // 8 KB
  __shared__ unsigned char Bs[64 * 128];  // 8 KB
  const int l = threadIdx.x;              // 0..63, one wave
  const int m = l & 15, q = l >> 4, s = l & 7;

  // triangular decode over 128x128 tile grid: start(r) = r*128 - r(r-1)/2
  const int bid = blockIdx.x;
  int rt = (int)((257.0f - sqrtf(66049.0f - 8.0f * (float)bid)) * 0.5f);
  rt = rt < 0 ? 0 : (rt > 127 ? 127 : rt);
  while (rt > 0 && (rt * 128 - rt * (rt - 1) / 2) > bid) --rt;
  while (rt < 127 && ((rt + 1) * 128 - (rt + 1) * rt / 2) <= bid) ++rt;
  const int ct = rt + (bid - (rt * 128 - rt * (rt - 1) / 2));
  const bool diag = (rt == ct);

  floatx4 acc[4][4] = {};

  const unsigned char* gA = xn + (size_t)rt * 64 * ND;
  const unsigned char* gB = xn + (size_t)ct * 64 * ND;

  // staging: lane l -> (row slab*8 + (l>>3), 16B chunk l&7), swizzled slot
  const int crow = l >> 3;                    // 0..7
  const int coff = (l & 7) * 16;
  const int la = crow * 128 + ((l & 7) ^ crow) * 16;  // + slab*1024

  // fragment read offsets (swizzled): row l&15, k-chunks 2q, 2q+1
  const int fo0 = ((2 * q + 0) ^ s) * 16;
  const int fo1 = ((2 * q + 1) ^ s) * 16;

  int4v pA[8], pB[8];
#pragma unroll
  for (int i = 0; i < 8; ++i) {  // prefetch kt=0 (8 slabs x 8 rows)
    const size_t go = (size_t)(i * 8 + crow) * ND + coff;
    pA[i] = *(const int4v*)(gA + go);
    if (!diag) pB[i] = *(const int4v*)(gB + go);
  }

#pragma unroll 1  // rolled: one live prefetch set (no hoist -> no spill)
  for (int kt = 0; kt < 4; ++kt) {
#pragma unroll
    for (int i = 0; i < 8; ++i) {  // stage current kt into private slab
      *(int4v*)(As + i * 1024 + la) = pA[i];
      if (!diag) *(int4v*)(Bs + i * 1024 + la) = pB[i];
    }
    if (kt < 3) {  // prefetch kt+1 — in flight across this kt's reads+MFMAs
      const int kb = (kt + 1) * 128;
#pragma unroll
      for (int i = 0; i < 8; ++i) {
        const size_t go = (size_t)(i * 8 + crow) * ND + kb + coff;
        pA[i] = *(const int4v*)(gA + go);
        if (!diag) pB[i] = *(const int4v*)(gB + go);
      }
    }
    const unsigned char* Ab = As;
    const unsigned char* Bb = diag ? As : Bs;
    int8v af0, af1, af2, af3, bf0, bf1, bf2, bf3;
    {
      const unsigned char* pa0 = Ab + (0 * 16 + m) * 128;
      const unsigned char* pa1 = Ab + (1 * 16 + m) * 128;
      const unsigned char* pa2 = Ab + (2 * 16 + m) * 128;
      const unsigned char* pa3 = Ab + (3 * 16 + m) * 128;
      const unsigned char* pb0 = Bb + (0 * 16 + m) * 128;
      const unsigned char* pb1 = Bb + (1 * 16 + m) * 128;
      const unsigned char* pb2 = Bb + (2 * 16 + m) * 128;
      const unsigned char* pb3 = Bb + (3 * 16 + m) * 128;
      af0 = __builtin_shufflevector(*(const int4v*)(pa0 + fo0),
                                    *(const int4v*)(pa0 + fo1), 0,1,2,3,4,5,6,7);
      af1 = __builtin_shufflevector(*(const int4v*)(pa1 + fo0),
                                    *(const int4v*)(pa1 + fo1), 0,1,2,3,4,5,6,7);
      af2 = __builtin_shufflevector(*(const int4v*)(pa2 + fo0),
                                    *(const int4v*)(pa2 + fo1), 0,1,2,3,4,5,6,7);
      af3 = __builtin_shufflevector(*(const int4v*)(pa3 + fo0),
                                    *(const int4v*)(pa3 + fo1), 0,1,2,3,4,5,6,7);
      bf0 = __builtin_shufflevector(*(const int4v*)(pb0 + fo0),
                                    *(const int4v*)(pb0 + fo1), 0,1,2,3,4,5,6,7);
      bf1 = __builtin_shufflevector(*(const int4v*)(pb1 + fo0),
                                    *(const int4v*)(pb1 + fo1), 0,1,2,3,4,5,6,7);
      bf2 = __builtin_shufflevector(*(const int4v*)(pb2 + fo0),
                                    *(const int4v*)(pb2 + fo1), 0,1,2,3,4,5,6,7);
      bf3 = __builtin_shufflevector(*(const int4v*)(pb3 + fo0),
                                    *(const int4v*)(pb3 + fo1), 0,1,2,3,4,5,6,7);
    }
#define MFMA_ROW(mt, afv)                                                     \
  acc[mt][0] = __builtin_amdgcn_mfma_scale_f32_16x16x128_f8f6f4(              \
      afv, bf0, acc[mt][0], 0, 0, 0, SCALE1, 0, SCALE1);                      \
  acc[mt][1] = __builtin_amdgcn_mfma_scale_f32_16x16x128_f8f6f4(              \
      afv, bf1, acc[mt][1], 0, 0, 0, SCALE1, 0, SCALE1);                      \
  acc[mt][2] = __builtin_amdgcn_mfma_scale_f32_16x16x128_f8f6f4(              \
      afv, bf2, acc[mt][2], 0, 0, 0, SCALE1, 0, SCALE1);                      \
  acc[mt][3] = __builtin_amdgcn_mfma_scale_f32_16x16x128_f8f6f4(              \
      afv, bf3, acc[mt][3], 0, 0, 0, SCALE1, 0, SCALE1)
    MFMA_ROW(0, af0);
    MFMA_ROW(1, af1);
    MFMA_ROW(2, af2);
    MFMA_ROW(3, af3);
#undef MFMA_ROW
    // no barrier: WAR on the private slab is a same-wave lgkmcnt dependency
  }

  // epilogue: s = 2*acc; masked cols ((c-r)%B==0) store pos, skip sums.
  // Row sums always; col sums + pos mirror only on off-diagonal tiles.
  const int r0 = rt * 64;
  const int c0 = ct * 64;
  float cs[4] = {0.f, 0.f, 0.f, 0.f};
#pragma unroll
  for (int mt = 0; mt < 4; ++mt) {
    float rs[4] = {0.f, 0.f, 0.f, 0.f};
#pragma unroll
    for (int nt = 0; nt < 4; ++nt) {
      const int c = c0 + nt * 16 + m;  // C layout: col = lane&15
#pragma unroll
      for (int reg = 0; reg < 4; ++reg) {
        const int r = r0 + mt * 16 + q * 4 + reg;  // row = quad*4 + reg
        const float sv = acc[mt][nt][reg] * 2.0f;
        if (((c - r) & (NB - 1)) == 0) {
          pos[r * NV + (c >> 11)] = sv;
          if (!diag) pos[c * NV + (r >> 11)] = sv;
        } else {
          const float e = __expf(sv);
          rs[reg] += e;
          cs[nt] += e;
        }
      }
    }
#pragma unroll
    for (int off = 1; off < 16; off <<= 1) {
#pragma unroll
      for (int reg = 0; reg < 4; ++reg) rs[reg] += __shfl_xor(rs[reg], off, 64);
    }
    if (m < 4) atomicAdd(&sumexp[r0 + mt * 16 + q * 4 + m], rs[m]);
  }
  if (!diag) {
#pragma unroll
    for (int nt = 0; nt < 4; ++nt) {
      cs[nt] += __shfl_xor(cs[nt], 16, 64);
      cs[nt] += __shfl_xor(cs[nt], 32, 64);
    }
    if (q == 0) {
#pragma unroll
      for (int nt = 0; nt < 4; ++nt)
        atomicAdd(&sumexp[c0 + nt * 16 + m], cs[nt]);
    }
  }
}

// ---------------- finalize: scalar loss -------------------------------------
__global__ __launch_bounds__(256) void finalize_k(
    const float* __restrict__ sumexp, const float* __restrict__ pos,
    float* __restrict__ out) {
  const int r = blockIdx.x * 256 + threadIdx.x;
  const float se = sumexp[r];
  const int i = r >> 11;
  float local = 0.0f;
#pragma unroll
  for (int j = 0; j < NV; ++j) {
    if (j == i) continue;
    const float p = pos[r * NV + j];
    local += logf(__expf(p) + se) - p;
  }
  local *= (1.0f / NB);
#pragma unroll
  for (int off = 32; off > 0; off >>= 1) local += __shfl_xor(local, off, 64);
  if ((threadIdx.x & 63) == 0) atomicAdd(out, local);
}

extern "C" void kernel_launch(void* const* d_in, const int* in_sizes, int n_in,
                              void* d_out, int out_size, void* d_ws,
                              size_t ws_size, hipStream_t stream) {
  const float* x = (const float*)d_in[0];
  float* out = (float*)d_out;
  char* ws = (char*)d_ws;
  unsigned char* xn = (unsigned char*)ws;                 // 4 MB fp8
  float* sumexp = (float*)(ws + (size_t)NN * ND);         // 32 KB
  float* pos = (float*)(ws + (size_t)NN * ND + NN * 4);   // 128 KB

  normalize_k<<<NN / 4, 256, 0, stream>>>(x, xn, sumexp, out);
  sim_k<<<128 * 129 / 2, 64, 0, stream>>>(xn, sumexp, pos);
  finalize_k<<<NN / 256, 256, 0, stream>>>(sumexp, pos, out);
}